// Round 2
// baseline (771.724 us; speedup 1.0000x reference)
//
#include <hip/hip_runtime.h>

#define EPSI 1e-5f

__device__ __forceinline__ float lrelu(float x) { return x > 0.f ? x : 0.01f * x; }

// Block-wide sum of (a,b). blockDim.x == 256. Result broadcast to all threads.
__device__ __forceinline__ float2 block_reduce_sum2(float a, float b) {
    #pragma unroll
    for (int off = 1; off < 64; off <<= 1) {
        a += __shfl_xor(a, off, 64);
        b += __shfl_xor(b, off, 64);
    }
    __shared__ float lds[8];
    const int t = threadIdx.x;
    if ((t & 63) == 0) { lds[2 * (t >> 6)] = a; lds[2 * (t >> 6) + 1] = b; }
    __syncthreads();
    a = lds[0] + lds[2] + lds[4] + lds[6];
    b = lds[1] + lds[3] + lds[5] + lds[7];
    return make_float2(a, b);
}

// ---------------- K1: conv1(3->16, 2x2 s2) + InstanceNorm + lrelu ----------------
// grid: B*16 blocks, 256 threads. plane 64x64 = 4096, 16 outputs/thread.
__global__ __launch_bounds__(256) void k1_conv_in(const float* __restrict__ x,
                                                  const float* __restrict__ w1,
                                                  float* __restrict__ h1) {
    const int b = blockIdx.x;
    const int n = b >> 4, co = b & 15;
    const int t = threadIdx.x;
    float w[3][2][2];
    #pragma unroll
    for (int ic = 0; ic < 3; ++ic)
        #pragma unroll
        for (int kh = 0; kh < 2; ++kh)
            #pragma unroll
            for (int kw = 0; kw < 2; ++kw)
                w[ic][kh][kw] = w1[((co * 3 + ic) * 2 + kh) * 2 + kw];
    const float* xn = x + (size_t)n * 3 * 128 * 128;
    float r[16];
    float s1 = 0.f, s2 = 0.f;
    #pragma unroll
    for (int i = 0; i < 16; ++i) {
        const int idx = t + 256 * i;
        const int oy = idx >> 6, ox = idx & 63;
        float acc = 0.f;
        #pragma unroll
        for (int ic = 0; ic < 3; ++ic) {
            const float2* r0 = (const float2*)(xn + ic * 16384 + (2 * oy) * 128);
            const float2* r1 = (const float2*)(xn + ic * 16384 + (2 * oy + 1) * 128);
            const float2 v0 = r0[ox], v1 = r1[ox];
            acc += v0.x * w[ic][0][0] + v0.y * w[ic][0][1] + v1.x * w[ic][1][0] + v1.y * w[ic][1][1];
        }
        r[i] = acc;
        s1 += acc; s2 += acc * acc;
    }
    const float2 s = block_reduce_sum2(s1, s2);
    const float mean = s.x * (1.f / 4096.f);
    const float var = s.y * (1.f / 4096.f) - mean * mean;
    const float sc = rsqrtf(var + EPSI);
    float* o = h1 + ((size_t)n * 16 + co) * 4096;
    #pragma unroll
    for (int i = 0; i < 16; ++i)
        o[t + 256 * i] = lrelu((r[i] - mean) * sc);
}

// ---------------- K2: conv2(16->32) + IN + lrelu, co-grouped (G=8) ---------------
// grid: B*4 blocks, 256 threads. Each block: one n, 8 co, full 32x32 plane.
// 4 px/thread/co. Input h1_n read exactly once per block (256KB).
__global__ __launch_bounds__(256) void k2_conv_in(const float* __restrict__ h1,
                                                  const float* __restrict__ w2,
                                                  float* __restrict__ h2) {
    const int n = blockIdx.x >> 2, cg = blockIdx.x & 3;
    const int t = threadIdx.x;
    __shared__ float wl[8 * 16 * 4];   // [co_local][ic][2][2]
    __shared__ float red[4][8][2];
    #pragma unroll
    for (int i = t; i < 512; i += 256) {
        const int j = i >> 6, rest = i & 63;   // rest = ic*4 + k
        wl[i] = w2[(size_t)(cg * 8 + j) * 144 + rest];  // w2 co-stride 36*4=144, ic<16
    }
    __syncthreads();
    const float* h1n = h1 + (size_t)n * 16 * 4096;
    const int oyb = t >> 5, ox = t & 31;      // oy = oyb + 8q
    float acc[8][4] = {};
    #pragma unroll
    for (int ic = 0; ic < 16; ++ic) {
        const float* p = h1n + ic * 4096;
        #pragma unroll
        for (int q = 0; q < 4; ++q) {
            const int oy = oyb + 8 * q;
            const float2 v0 = ((const float2*)(p + (2 * oy) * 64))[ox];
            const float2 v1 = ((const float2*)(p + (2 * oy + 1) * 64))[ox];
            #pragma unroll
            for (int j = 0; j < 8; ++j) {
                const float* wj = &wl[(j * 16 + ic) * 4];
                acc[j][q] += v0.x * wj[0] + v0.y * wj[1] + v1.x * wj[2] + v1.y * wj[3];
            }
        }
    }
    const int w = t >> 6, l = t & 63;
    #pragma unroll
    for (int j = 0; j < 8; ++j) {
        float s1 = acc[j][0] + acc[j][1] + acc[j][2] + acc[j][3];
        float s2 = acc[j][0] * acc[j][0] + acc[j][1] * acc[j][1] +
                   acc[j][2] * acc[j][2] + acc[j][3] * acc[j][3];
        #pragma unroll
        for (int off = 1; off < 64; off <<= 1) {
            s1 += __shfl_xor(s1, off, 64);
            s2 += __shfl_xor(s2, off, 64);
        }
        if (l == 0) { red[w][j][0] = s1; red[w][j][1] = s2; }
    }
    __syncthreads();
    #pragma unroll
    for (int j = 0; j < 8; ++j) {
        const float s1 = red[0][j][0] + red[1][j][0] + red[2][j][0] + red[3][j][0];
        const float s2 = red[0][j][1] + red[1][j][1] + red[2][j][1] + red[3][j][1];
        const float mean = s1 * (1.f / 1024.f);
        const float var = s2 * (1.f / 1024.f) - mean * mean;
        const float sc = rsqrtf(var + EPSI);
        float* o = h2 + ((size_t)n * 32 + cg * 8 + j) * 1024;
        #pragma unroll
        for (int q = 0; q < 4; ++q)
            o[t + 256 * q] = lrelu((acc[j][q] - mean) * sc);
    }
}

// ---------------- K3: conv3(32->64) + IN + lrelu, co-grouped (G=16) --------------
// grid: B*4 blocks, 256 threads. Each block: one n, 16 co, full 16x16 plane (1 px/thr).
__global__ __launch_bounds__(256) void k3_conv_in(const float* __restrict__ h2,
                                                  const float* __restrict__ w3,
                                                  float* __restrict__ h3) {
    const int n = blockIdx.x >> 2, cg = blockIdx.x & 3;
    const int t = threadIdx.x;
    __shared__ float wl[16 * 32 * 4];  // [co_local][ic][2][2]
    __shared__ float red[4][16][2];
    #pragma unroll
    for (int i = t; i < 2048; i += 256)
        wl[i] = w3[(size_t)cg * 2048 + i];   // co block contiguous: 16 co * 128
    __syncthreads();
    const float* h2n = h2 + (size_t)n * 32 * 1024;
    const int oy = t >> 4, ox = t & 15;
    float acc[16] = {};
    #pragma unroll 8
    for (int ic = 0; ic < 32; ++ic) {
        const float* p = h2n + ic * 1024 + (2 * oy) * 32;
        const float2 v0 = ((const float2*)p)[ox];
        const float2 v1 = ((const float2*)(p + 32))[ox];
        #pragma unroll
        for (int j = 0; j < 16; ++j) {
            const float* wj = &wl[(j * 32 + ic) * 4];
            acc[j] += v0.x * wj[0] + v0.y * wj[1] + v1.x * wj[2] + v1.y * wj[3];
        }
    }
    const int w = t >> 6, l = t & 63;
    #pragma unroll
    for (int j = 0; j < 16; ++j) {
        float s1 = acc[j], s2 = acc[j] * acc[j];
        #pragma unroll
        for (int off = 1; off < 64; off <<= 1) {
            s1 += __shfl_xor(s1, off, 64);
            s2 += __shfl_xor(s2, off, 64);
        }
        if (l == 0) { red[w][j][0] = s1; red[w][j][1] = s2; }
    }
    __syncthreads();
    #pragma unroll
    for (int j = 0; j < 16; ++j) {
        const float s1 = red[0][j][0] + red[1][j][0] + red[2][j][0] + red[3][j][0];
        const float s2 = red[0][j][1] + red[1][j][1] + red[2][j][1] + red[3][j][1];
        const float mean = s1 * (1.f / 256.f);
        const float var = s2 * (1.f / 256.f) - mean * mean;
        const float sc = rsqrtf(var + EPSI);
        h3[((size_t)n * 64 + cg * 16 + j) * 256 + t] = lrelu((acc[j] - mean) * sc);
    }
}

// ---------------- K4: conv4(64->128) + IN + lrelu, co-grouped (G=32) -------------
// grid: B*4 blocks, 256 threads (4 waves). Wave w: 8 co, lane = pixel (8x8=64).
__global__ __launch_bounds__(256) void k4_conv_in(const float* __restrict__ h3,
                                                  const float* __restrict__ w4,
                                                  float* __restrict__ h4) {
    const int n = blockIdx.x >> 2, cg = blockIdx.x & 3;
    const int t = threadIdx.x;
    __shared__ float wl[32 * 64 * 4];  // [co_local][ic][2][2] = 32KB
    #pragma unroll
    for (int i = t; i < 8192; i += 256)
        wl[i] = w4[(size_t)cg * 8192 + i];
    __syncthreads();
    const int w = t >> 6, l = t & 63;
    const int oy = l >> 3, ox = l & 7;
    const float* h3n = h3 + (size_t)n * 64 * 256;
    float acc[8] = {};
    #pragma unroll 8
    for (int ic = 0; ic < 64; ++ic) {
        const float* p = h3n + ic * 256 + (2 * oy) * 16;
        const float2 v0 = ((const float2*)p)[ox];
        const float2 v1 = ((const float2*)(p + 16))[ox];
        #pragma unroll
        for (int jj = 0; jj < 8; ++jj) {
            const float* wj = &wl[((w * 8 + jj) * 64 + ic) * 4];
            acc[jj] += v0.x * wj[0] + v0.y * wj[1] + v1.x * wj[2] + v1.y * wj[3];
        }
    }
    #pragma unroll
    for (int jj = 0; jj < 8; ++jj) {
        float s1 = acc[jj], s2 = acc[jj] * acc[jj];
        #pragma unroll
        for (int off = 1; off < 64; off <<= 1) {
            s1 += __shfl_xor(s1, off, 64);
            s2 += __shfl_xor(s2, off, 64);
        }
        const float mean = s1 * (1.f / 64.f);
        const float var = s2 * (1.f / 64.f) - mean * mean;
        const float sc = rsqrtf(var + EPSI);
        const int co = cg * 32 + w * 8 + jj;
        h4[((size_t)n * 128 + co) * 64 + l] = lrelu((acc[jj] - mean) * sc);
    }
}

// ---------------- K5: FC1 split-K GEMM, partials to workspace --------------------
// C[256,1024] = A[256,8192] x W[1024,8192]^T. BM=BN=64, SK=16 (512 K each), BK=32.
// grid = 64 tiles * 16 sk = 1024 blocks, 256 threads, 4x4 acc/thread.
__global__ __launch_bounds__(256) void k5_fc1(const float* __restrict__ A,
                                              const float* __restrict__ W,
                                              float* __restrict__ Cp) {
    __shared__ float As[32][64];  // [kk][m], m-quad XOR-swizzled
    __shared__ float Bs[32][64];  // [kk][n], n-quad XOR-swizzled
    const int t = threadIdx.x;
    const int sk = blockIdx.x >> 6;
    const int tile = blockIdx.x & 63;
    const int mt = tile >> 4, nt = tile & 15;
    const int m0 = mt * 64, n0 = nt * 64;
    const int tx = t & 15;    // n quad 4*tx
    const int ty = t >> 4;    // m quad 4*ty
    const int lr = t >> 2, lq = t & 3;  // load: row, k-quad
    float acc[4][4] = {};
    const int kbeg = sk * 512;
    for (int k0 = kbeg; k0 < kbeg + 512; k0 += 32) {
        const float4 av0 = *(const float4*)(A + (size_t)(m0 + lr) * 8192 + k0 + 4 * lq);
        const float4 av1 = *(const float4*)(A + (size_t)(m0 + lr) * 8192 + k0 + 16 + 4 * lq);
        const float4 bv0 = *(const float4*)(W + (size_t)(n0 + lr) * 8192 + k0 + 4 * lq);
        const float4 bv1 = *(const float4*)(W + (size_t)(n0 + lr) * 8192 + k0 + 16 + 4 * lq);
        __syncthreads();
        {
            const float a0[4] = {av0.x, av0.y, av0.z, av0.w};
            const float a1[4] = {av1.x, av1.y, av1.z, av1.w};
            const float b0[4] = {bv0.x, bv0.y, bv0.z, bv0.w};
            const float b1[4] = {bv1.x, bv1.y, bv1.z, bv1.w};
            const int q = lr >> 2, r = lr & 3;
            #pragma unroll
            for (int j = 0; j < 4; ++j) {
                const int kkA = 4 * lq + j, kkB = kkA + 16;
                As[kkA][(((q ^ kkA) & 15) << 2) | r] = a0[j];
                As[kkB][(((q ^ kkB) & 15) << 2) | r] = a1[j];
                Bs[kkA][(((q ^ kkA) & 15) << 2) | r] = b0[j];
                Bs[kkB][(((q ^ kkB) & 15) << 2) | r] = b1[j];
            }
        }
        __syncthreads();
        #pragma unroll
        for (int kk = 0; kk < 32; ++kk) {
            const float4 a4 = *(const float4*)&As[kk][((ty ^ kk) & 15) << 2];
            const float4 b4 = *(const float4*)&Bs[kk][((tx ^ kk) & 15) << 2];
            const float a[4] = {a4.x, a4.y, a4.z, a4.w};
            const float b[4] = {b4.x, b4.y, b4.z, b4.w};
            #pragma unroll
            for (int i = 0; i < 4; ++i)
                #pragma unroll
                for (int j = 0; j < 4; ++j)
                    acc[i][j] += a[i] * b[j];
        }
    }
    #pragma unroll
    for (int i = 0; i < 4; ++i) {
        const int m = m0 + 4 * ty + i;
        float4 v = make_float4(acc[i][0], acc[i][1], acc[i][2], acc[i][3]);
        *(float4*)(Cp + ((size_t)sk * 256 + m) * 1024 + n0 + 4 * tx) = v;
    }
}

// ---------------- R5: reduce split-K partials + bias + lrelu ---------------------
__global__ __launch_bounds__(256) void r5_reduce(const float* __restrict__ Cp,
                                                 const float* __restrict__ bias,
                                                 float* __restrict__ h5) {
    const int gid = blockIdx.x * 256 + threadIdx.x;  // 256*1024 total
    const int m = gid >> 10, nn = gid & 1023;
    float s = 0.f;
    #pragma unroll
    for (int sk = 0; sk < 16; ++sk)
        s += Cp[((size_t)sk * 256 + m) * 1024 + nn];
    h5[gid] = lrelu(s + bias[nn]);
}

// ---------------- K6: FC2 [256,1024]x[1,1024]^T + bias ---------------------------
__global__ __launch_bounds__(256) void k6_fc2(const float* __restrict__ h5,
                                              const float* __restrict__ w,
                                              const float* __restrict__ b,
                                              float* __restrict__ out) {
    const int n = blockIdx.x, t = threadIdx.x;
    const float* r = h5 + (size_t)n * 1024;
    float s = 0.f;
    #pragma unroll
    for (int i = 0; i < 4; ++i) s += r[t + 256 * i] * w[t + 256 * i];
    const float2 red = block_reduce_sum2(s, 0.f);
    if (t == 0) out[n] = red.x + b[0];
}

extern "C" void kernel_launch(void* const* d_in, const int* in_sizes, int n_in,
                              void* d_out, int out_size, void* d_ws, size_t ws_size,
                              hipStream_t stream) {
    (void)in_sizes; (void)n_in; (void)out_size; (void)ws_size;
    const float* x    = (const float*)d_in[0];
    // labels (d_in[1]) and conv biases (d_in[3,5,7,9]) cancel exactly under InstanceNorm
    const float* w1   = (const float*)d_in[2];
    const float* w2   = (const float*)d_in[4];
    const float* w3   = (const float*)d_in[6];
    const float* w4   = (const float*)d_in[8];
    const float* fcw1 = (const float*)d_in[10];
    const float* fcb1 = (const float*)d_in[11];
    const float* fcw2 = (const float*)d_in[12];
    const float* fcb2 = (const float*)d_in[13];
    float* out = (float*)d_out;
    float* bufA = (float*)d_ws;          // 16,777,216 floats (67.1 MB)
    float* bufB = bufA + 16777216;       //  8,388,608 floats (33.5 MB)
    float* h1 = bufA;                    // 16.7M floats
    float* h2 = bufB;                    // 8.4M used
    float* h3 = bufA;                    // h1 dead
    float* h4 = bufB;                    // h2 dead
    float* Cp = bufA;                    // h3 dead at k5; 4.2M floats
    float* h5 = bufA + 4194304;          // 262144 floats
    k1_conv_in<<<256 * 16, 256, 0, stream>>>(x, w1, h1);
    k2_conv_in<<<256 * 4, 256, 0, stream>>>(h1, w2, h2);
    k3_conv_in<<<256 * 4, 256, 0, stream>>>(h2, w3, h3);
    k4_conv_in<<<256 * 4, 256, 0, stream>>>(h3, w4, h4);
    k5_fc1<<<1024, 256, 0, stream>>>(h4, fcw1, Cp);
    r5_reduce<<<1024, 256, 0, stream>>>(Cp, fcb1, h5);
    k6_fc2<<<256, 256, 0, stream>>>(h5, fcw2, fcb2, out);
}

// Round 3
// 298.391 us; speedup vs baseline: 2.5863x; 2.5863x over previous
//
#include <hip/hip_runtime.h>

#define EPSI 1e-5f

__device__ __forceinline__ float lrelu(float x) { return x > 0.f ? x : 0.01f * x; }

// Block-wide sum of (a,b). blockDim.x == 256. Result broadcast to all threads.
__device__ __forceinline__ float2 block_reduce_sum2(float a, float b) {
    #pragma unroll
    for (int off = 1; off < 64; off <<= 1) {
        a += __shfl_xor(a, off, 64);
        b += __shfl_xor(b, off, 64);
    }
    __shared__ float lds[8];
    const int t = threadIdx.x;
    if ((t & 63) == 0) { lds[2 * (t >> 6)] = a; lds[2 * (t >> 6) + 1] = b; }
    __syncthreads();
    a = lds[0] + lds[2] + lds[4] + lds[6];
    b = lds[1] + lds[3] + lds[5] + lds[7];
    return make_float2(a, b);
}

// ---------------- K1: conv1(3->16, 2x2 s2) + InstanceNorm + lrelu ----------------
// grid: B*16 blocks, 256 threads. plane 64x64 = 4096, 16 outputs/thread.
__global__ __launch_bounds__(256) void k1_conv_in(const float* __restrict__ x,
                                                  const float* __restrict__ w1,
                                                  float* __restrict__ h1) {
    const int b = blockIdx.x;
    const int n = b >> 4, co = b & 15;
    const int t = threadIdx.x;
    float w[3][2][2];
    #pragma unroll
    for (int ic = 0; ic < 3; ++ic)
        #pragma unroll
        for (int kh = 0; kh < 2; ++kh)
            #pragma unroll
            for (int kw = 0; kw < 2; ++kw)
                w[ic][kh][kw] = w1[((co * 3 + ic) * 2 + kh) * 2 + kw];
    const float* xn = x + (size_t)n * 3 * 128 * 128;
    float r[16];
    float s1 = 0.f, s2 = 0.f;
    #pragma unroll 4
    for (int i = 0; i < 16; ++i) {
        const int idx = t + 256 * i;
        const int oy = idx >> 6, ox = idx & 63;
        float acc = 0.f;
        #pragma unroll
        for (int ic = 0; ic < 3; ++ic) {
            const float2* r0 = (const float2*)(xn + ic * 16384 + (2 * oy) * 128);
            const float2* r1 = (const float2*)(xn + ic * 16384 + (2 * oy + 1) * 128);
            const float2 v0 = r0[ox], v1 = r1[ox];
            acc += v0.x * w[ic][0][0] + v0.y * w[ic][0][1] + v1.x * w[ic][1][0] + v1.y * w[ic][1][1];
        }
        r[i] = acc;
        s1 += acc; s2 += acc * acc;
    }
    const float2 s = block_reduce_sum2(s1, s2);
    const float mean = s.x * (1.f / 4096.f);
    const float var = s.y * (1.f / 4096.f) - mean * mean;
    const float sc = rsqrtf(var + EPSI);
    float* o = h1 + ((size_t)n * 16 + co) * 4096;
    #pragma unroll 4
    for (int i = 0; i < 16; ++i)
        o[t + 256 * i] = lrelu((r[i] - mean) * sc);
}

// ---------------- K2: conv2(16->32) + IN + lrelu, co-grouped (G=8) ---------------
// grid: B*4 blocks, 256 threads. Block: one n, 8 co, full 32x32 plane, 4 px/thread.
// Limited unroll to keep VGPR < 128 (round-1 full unroll spilled: 1.4GB scratch).
__global__ __launch_bounds__(256) void k2_conv_in(const float* __restrict__ h1,
                                                  const float* __restrict__ w2,
                                                  float* __restrict__ h2) {
    const int n = blockIdx.x >> 2, cg = blockIdx.x & 3;
    const int t = threadIdx.x;
    __shared__ float wl[8 * 16 * 4];   // [co_local][ic][2][2]
    __shared__ float red[4][8][2];
    for (int i = t; i < 512; i += 256) {
        const int j = i >> 6, rest = i & 63;   // rest = ic*4 + k
        wl[i] = w2[(size_t)(cg * 8 + j) * 144 + rest];  // w2 co-stride 36*4=144, ic<16
    }
    __syncthreads();
    const float* h1n = h1 + (size_t)n * 16 * 4096;
    const int oyb = t >> 5, ox = t & 31;      // oy = oyb + 8q
    float acc[8][4] = {};
    #pragma unroll 2
    for (int ic = 0; ic < 16; ++ic) {
        const float* p = h1n + ic * 4096;
        float2 v0[4], v1[4];
        #pragma unroll
        for (int q = 0; q < 4; ++q) {
            const int oy = oyb + 8 * q;
            v0[q] = ((const float2*)(p + (2 * oy) * 64))[ox];
            v1[q] = ((const float2*)(p + (2 * oy + 1) * 64))[ox];
        }
        #pragma unroll
        for (int j = 0; j < 8; ++j) {
            const float4 wv = *(const float4*)&wl[(j * 16 + ic) * 4];
            #pragma unroll
            for (int q = 0; q < 4; ++q)
                acc[j][q] += v0[q].x * wv.x + v0[q].y * wv.y + v1[q].x * wv.z + v1[q].y * wv.w;
        }
    }
    const int w = t >> 6, l = t & 63;
    #pragma unroll 2
    for (int j = 0; j < 8; ++j) {
        float s1 = acc[j][0] + acc[j][1] + acc[j][2] + acc[j][3];
        float s2 = acc[j][0] * acc[j][0] + acc[j][1] * acc[j][1] +
                   acc[j][2] * acc[j][2] + acc[j][3] * acc[j][3];
        #pragma unroll
        for (int off = 1; off < 64; off <<= 1) {
            s1 += __shfl_xor(s1, off, 64);
            s2 += __shfl_xor(s2, off, 64);
        }
        if (l == 0) { red[w][j][0] = s1; red[w][j][1] = s2; }
    }
    __syncthreads();
    #pragma unroll 2
    for (int j = 0; j < 8; ++j) {
        const float s1 = red[0][j][0] + red[1][j][0] + red[2][j][0] + red[3][j][0];
        const float s2 = red[0][j][1] + red[1][j][1] + red[2][j][1] + red[3][j][1];
        const float mean = s1 * (1.f / 1024.f);
        const float var = s2 * (1.f / 1024.f) - mean * mean;
        const float sc = rsqrtf(var + EPSI);
        float* o = h2 + ((size_t)n * 32 + cg * 8 + j) * 1024;
        #pragma unroll
        for (int q = 0; q < 4; ++q)
            o[t + 256 * q] = lrelu((acc[j][q] - mean) * sc);
    }
}

// ---------------- K3: conv3(32->64) + IN + lrelu, 2n x 16co per block ------------
// grid: (B/2)*4 = 512 blocks, 256 threads. Thread: 1 px (16x16), 2 samples, 16 co.
// Each b128 weight read feeds 2n*4 = 8 FMA.
__global__ __launch_bounds__(256) void k3_conv_in(const float* __restrict__ h2,
                                                  const float* __restrict__ w3,
                                                  float* __restrict__ h3) {
    const int n0 = (blockIdx.x >> 2) * 2, cg = blockIdx.x & 3;
    const int t = threadIdx.x;
    __shared__ float wl[16 * 32 * 4];  // 8KB: [co_local][ic][2][2]
    __shared__ float red[4][16][2][2]; // [wave][co][n][s1/s2]
    for (int i = t; i < 2048; i += 256)
        wl[i] = w3[(size_t)cg * 2048 + i];   // 16 co * 128, contiguous
    __syncthreads();
    const int oy = t >> 4, ox = t & 15;
    float acc[16][2] = {};
    #pragma unroll 2
    for (int ic = 0; ic < 32; ++ic) {
        float2 v0[2], v1[2];
        #pragma unroll
        for (int nn = 0; nn < 2; ++nn) {
            const float* p = h2 + ((size_t)(n0 + nn) * 32 + ic) * 1024 + (2 * oy) * 32;
            v0[nn] = ((const float2*)p)[ox];
            v1[nn] = ((const float2*)(p + 32))[ox];
        }
        #pragma unroll
        for (int j = 0; j < 16; ++j) {
            const float4 wv = *(const float4*)&wl[(j * 32 + ic) * 4];
            #pragma unroll
            for (int nn = 0; nn < 2; ++nn)
                acc[j][nn] += v0[nn].x * wv.x + v0[nn].y * wv.y + v1[nn].x * wv.z + v1[nn].y * wv.w;
        }
    }
    const int w = t >> 6, l = t & 63;
    #pragma unroll 2
    for (int j = 0; j < 16; ++j) {
        #pragma unroll
        for (int nn = 0; nn < 2; ++nn) {
            float s1 = acc[j][nn], s2 = acc[j][nn] * acc[j][nn];
            #pragma unroll
            for (int off = 1; off < 64; off <<= 1) {
                s1 += __shfl_xor(s1, off, 64);
                s2 += __shfl_xor(s2, off, 64);
            }
            if (l == 0) { red[w][j][nn][0] = s1; red[w][j][nn][1] = s2; }
        }
    }
    __syncthreads();
    #pragma unroll 2
    for (int j = 0; j < 16; ++j) {
        #pragma unroll
        for (int nn = 0; nn < 2; ++nn) {
            const float s1 = red[0][j][nn][0] + red[1][j][nn][0] + red[2][j][nn][0] + red[3][j][nn][0];
            const float s2 = red[0][j][nn][1] + red[1][j][nn][1] + red[2][j][nn][1] + red[3][j][nn][1];
            const float mean = s1 * (1.f / 256.f);
            const float var = s2 * (1.f / 256.f) - mean * mean;
            const float sc = rsqrtf(var + EPSI);
            h3[((size_t)(n0 + nn) * 64 + cg * 16 + j) * 256 + t] = lrelu((acc[j][nn] - mean) * sc);
        }
    }
}

// ---------------- K4: conv4(64->128) + IN + lrelu, 4n x 32co per block -----------
// grid: (B/4)*4 = 256 blocks, 256 threads. Wave w: co [8w,8w+8), lane = px (8x8),
// thread loops 4 samples. IN reduce = pure wave shuffle (plane == 64 lanes).
__global__ __launch_bounds__(256) void k4_conv_in(const float* __restrict__ h3,
                                                  const float* __restrict__ w4,
                                                  float* __restrict__ h4) {
    const int n0 = (blockIdx.x >> 2) * 4, cg = blockIdx.x & 3;
    const int t = threadIdx.x;
    __shared__ float wl[32 * 64 * 4];  // 32KB: [co_local][ic][2][2]
    for (int i = t; i < 8192; i += 256)
        wl[i] = w4[(size_t)cg * 8192 + i];
    __syncthreads();
    const int w = t >> 6, l = t & 63;
    const int oy = l >> 3, ox = l & 7;
    float acc[8][4] = {};
    #pragma unroll 2
    for (int ic = 0; ic < 64; ++ic) {
        float2 v0[4], v1[4];
        #pragma unroll
        for (int nn = 0; nn < 4; ++nn) {
            const float* p = h3 + ((size_t)(n0 + nn) * 64 + ic) * 256 + (2 * oy) * 16;
            v0[nn] = ((const float2*)p)[ox];
            v1[nn] = ((const float2*)(p + 16))[ox];
        }
        #pragma unroll
        for (int jj = 0; jj < 8; ++jj) {
            const float4 wv = *(const float4*)&wl[((w * 8 + jj) * 64 + ic) * 4];
            #pragma unroll
            for (int nn = 0; nn < 4; ++nn)
                acc[jj][nn] += v0[nn].x * wv.x + v0[nn].y * wv.y + v1[nn].x * wv.z + v1[nn].y * wv.w;
        }
    }
    #pragma unroll 2
    for (int jj = 0; jj < 8; ++jj) {
        #pragma unroll
        for (int nn = 0; nn < 4; ++nn) {
            float s1 = acc[jj][nn], s2 = acc[jj][nn] * acc[jj][nn];
            #pragma unroll
            for (int off = 1; off < 64; off <<= 1) {
                s1 += __shfl_xor(s1, off, 64);
                s2 += __shfl_xor(s2, off, 64);
            }
            const float mean = s1 * (1.f / 64.f);
            const float var = s2 * (1.f / 64.f) - mean * mean;
            const float sc = rsqrtf(var + EPSI);
            const int co = cg * 32 + w * 8 + jj;
            h4[((size_t)(n0 + nn) * 128 + co) * 64 + l] = lrelu((acc[jj][nn] - mean) * sc);
        }
    }
}

// ---------------- K5: FC1 split-K GEMM, partials to workspace --------------------
// C[256,1024] = A[256,8192] x W[1024,8192]^T. BM=BN=64, SK=16 (512 K each), BK=32.
// grid = 64 tiles * 16 sk = 1024 blocks, 256 threads, 4x4 acc/thread.
__global__ __launch_bounds__(256) void k5_fc1(const float* __restrict__ A,
                                              const float* __restrict__ W,
                                              float* __restrict__ Cp) {
    __shared__ float As[32][64];  // [kk][m], m-quad XOR-swizzled
    __shared__ float Bs[32][64];  // [kk][n], n-quad XOR-swizzled
    const int t = threadIdx.x;
    const int sk = blockIdx.x >> 6;
    const int tile = blockIdx.x & 63;
    const int mt = tile >> 4, nt = tile & 15;
    const int m0 = mt * 64, n0 = nt * 64;
    const int tx = t & 15;    // n quad 4*tx
    const int ty = t >> 4;    // m quad 4*ty
    const int lr = t >> 2, lq = t & 3;  // load: row, k-quad
    float acc[4][4] = {};
    const int kbeg = sk * 512;
    for (int k0 = kbeg; k0 < kbeg + 512; k0 += 32) {
        const float4 av0 = *(const float4*)(A + (size_t)(m0 + lr) * 8192 + k0 + 4 * lq);
        const float4 av1 = *(const float4*)(A + (size_t)(m0 + lr) * 8192 + k0 + 16 + 4 * lq);
        const float4 bv0 = *(const float4*)(W + (size_t)(n0 + lr) * 8192 + k0 + 4 * lq);
        const float4 bv1 = *(const float4*)(W + (size_t)(n0 + lr) * 8192 + k0 + 16 + 4 * lq);
        __syncthreads();
        {
            const float a0[4] = {av0.x, av0.y, av0.z, av0.w};
            const float a1[4] = {av1.x, av1.y, av1.z, av1.w};
            const float b0[4] = {bv0.x, bv0.y, bv0.z, bv0.w};
            const float b1[4] = {bv1.x, bv1.y, bv1.z, bv1.w};
            const int q = lr >> 2, r = lr & 3;
            #pragma unroll
            for (int j = 0; j < 4; ++j) {
                const int kkA = 4 * lq + j, kkB = kkA + 16;
                As[kkA][(((q ^ kkA) & 15) << 2) | r] = a0[j];
                As[kkB][(((q ^ kkB) & 15) << 2) | r] = a1[j];
                Bs[kkA][(((q ^ kkA) & 15) << 2) | r] = b0[j];
                Bs[kkB][(((q ^ kkB) & 15) << 2) | r] = b1[j];
            }
        }
        __syncthreads();
        #pragma unroll
        for (int kk = 0; kk < 32; ++kk) {
            const float4 a4 = *(const float4*)&As[kk][((ty ^ kk) & 15) << 2];
            const float4 b4 = *(const float4*)&Bs[kk][((tx ^ kk) & 15) << 2];
            const float a[4] = {a4.x, a4.y, a4.z, a4.w};
            const float b[4] = {b4.x, b4.y, b4.z, b4.w};
            #pragma unroll
            for (int i = 0; i < 4; ++i)
                #pragma unroll
                for (int j = 0; j < 4; ++j)
                    acc[i][j] += a[i] * b[j];
        }
    }
    #pragma unroll
    for (int i = 0; i < 4; ++i) {
        const int m = m0 + 4 * ty + i;
        float4 v = make_float4(acc[i][0], acc[i][1], acc[i][2], acc[i][3]);
        *(float4*)(Cp + ((size_t)sk * 256 + m) * 1024 + n0 + 4 * tx) = v;
    }
}

// ---------------- R5: reduce split-K partials + bias + lrelu ---------------------
__global__ __launch_bounds__(256) void r5_reduce(const float* __restrict__ Cp,
                                                 const float* __restrict__ bias,
                                                 float* __restrict__ h5) {
    const int gid = blockIdx.x * 256 + threadIdx.x;  // 256*1024 total
    const int m = gid >> 10, nn = gid & 1023;
    float s = 0.f;
    #pragma unroll
    for (int sk = 0; sk < 16; ++sk)
        s += Cp[((size_t)sk * 256 + m) * 1024 + nn];
    h5[gid] = lrelu(s + bias[nn]);
}

// ---------------- K6: FC2 [256,1024]x[1,1024]^T + bias ---------------------------
__global__ __launch_bounds__(256) void k6_fc2(const float* __restrict__ h5,
                                              const float* __restrict__ w,
                                              const float* __restrict__ b,
                                              float* __restrict__ out) {
    const int n = blockIdx.x, t = threadIdx.x;
    const float* r = h5 + (size_t)n * 1024;
    float s = 0.f;
    #pragma unroll
    for (int i = 0; i < 4; ++i) s += r[t + 256 * i] * w[t + 256 * i];
    const float2 red = block_reduce_sum2(s, 0.f);
    if (t == 0) out[n] = red.x + b[0];
}

extern "C" void kernel_launch(void* const* d_in, const int* in_sizes, int n_in,
                              void* d_out, int out_size, void* d_ws, size_t ws_size,
                              hipStream_t stream) {
    (void)in_sizes; (void)n_in; (void)out_size; (void)ws_size;
    const float* x    = (const float*)d_in[0];
    // labels (d_in[1]) and conv biases (d_in[3,5,7,9]) cancel exactly under InstanceNorm
    const float* w1   = (const float*)d_in[2];
    const float* w2   = (const float*)d_in[4];
    const float* w3   = (const float*)d_in[6];
    const float* w4   = (const float*)d_in[8];
    const float* fcw1 = (const float*)d_in[10];
    const float* fcb1 = (const float*)d_in[11];
    const float* fcw2 = (const float*)d_in[12];
    const float* fcb2 = (const float*)d_in[13];
    float* out = (float*)d_out;
    float* bufA = (float*)d_ws;          // 16,777,216 floats (67.1 MB)
    float* bufB = bufA + 16777216;       //  8,388,608 floats (33.5 MB)
    float* h1 = bufA;                    // 16.7M floats
    float* h2 = bufB;                    // 8.4M used
    float* h3 = bufA;                    // h1 dead
    float* h4 = bufB;                    // h2 dead
    float* Cp = bufA;                    // h3 dead at k5; 4.2M floats
    float* h5 = bufA + 4194304;          // 262144 floats
    k1_conv_in<<<256 * 16, 256, 0, stream>>>(x, w1, h1);
    k2_conv_in<<<256 * 4, 256, 0, stream>>>(h1, w2, h2);
    k3_conv_in<<<512, 256, 0, stream>>>(h2, w3, h3);
    k4_conv_in<<<256, 256, 0, stream>>>(h3, w4, h4);
    k5_fc1<<<1024, 256, 0, stream>>>(h4, fcw1, Cp);
    r5_reduce<<<1024, 256, 0, stream>>>(Cp, fcb1, h5);
    k6_fc2<<<256, 256, 0, stream>>>(h5, fcw2, fcb2, out);
}